// Round 1
// baseline (1151.419 us; speedup 1.0000x reference)
//
#include <hip/hip_runtime.h>
#include <math.h>

#define HF 128   // feature width
#define TN 32    // nodes per tile in the MLP kernel

// ---------------------------------------------------------------------------
// Phase 1: scatter-add edge messages into node accumulator (d_out used as agg)
// One thread per (edge, 4-feature chunk): float4 load from e, 4 f32 HW atomics.
// ---------------------------------------------------------------------------
__global__ void scatter_add_kernel(const float* __restrict__ e,
                                   const int* __restrict__ tgt,
                                   float* __restrict__ agg, int E) {
    int t = blockIdx.x * blockDim.x + threadIdx.x;
    int eid = t >> 5;          // edge id
    if (eid >= E) return;
    int c = t & 31;            // feature chunk (4 floats)
    int dst = tgt[eid];        // target node
    float4 val = *reinterpret_cast<const float4*>(e + (size_t)eid * HF + c * 4);
    float* p = agg + (size_t)dst * HF + c * 4;
    // coarse-grained device memory -> HW global_atomic_add_f32 is safe
    unsafeAtomicAdd(p + 0, val.x);
    unsafeAtomicAdd(p + 1, val.y);
    unsafeAtomicAdd(p + 2, val.z);
    unsafeAtomicAdd(p + 3, val.w);
}

// ---------------------------------------------------------------------------
// Phase 2: out = v + ( ssp(agg @ w1 + b1) @ w2 + b2 ), in place over agg rows.
// ssp(x) = softplus(x) - log(2), numerically stable both tails.
// ---------------------------------------------------------------------------
__device__ __forceinline__ float ssp(float x) {
    const float SHIFT = 0.69314718055994531f;
    return (x > 0.f) ? (x + log1pf(expf(-x)) - SHIFT)
                     : (log1pf(expf(x)) - SHIFT);
}

__device__ __forceinline__ void fma4(float4& acc, float a, const float4& w) {
    acc.x = fmaf(a, w.x, acc.x);
    acc.y = fmaf(a, w.y, acc.y);
    acc.z = fmaf(a, w.z, acc.z);
    acc.w = fmaf(a, w.w, acc.w);
}

__global__ __launch_bounds__(512) void mlp_kernel(
        float* __restrict__ data,       // agg in, final output out (same buffer; row-disjoint per block)
        const float* __restrict__ v,
        const float* __restrict__ w1, const float* __restrict__ b1,
        const float* __restrict__ w2, const float* __restrict__ b2,
        int N) {
    __shared__ float w1s[HF * HF];      // 64 KB
    __shared__ float w2s[HF * HF];      // 64 KB
    __shared__ float tile[TN][HF];      // 16 KB: agg tile, then reused for h tile

    int tid = threadIdx.x;
    float4* w1sv = (float4*)w1s;
    float4* w2sv = (float4*)w2s;
    const float4* w1v = (const float4*)w1;
    const float4* w2v = (const float4*)w2;
    for (int i = tid; i < HF * HF / 4; i += 512) {
        w1sv[i] = w1v[i];
        w2sv[i] = w2v[i];
    }

    int nl   = tid >> 5;   // node-local 0..15 (thread also handles nl+16)
    int fblk = tid & 31;   // 4-feature block
    float4 bb1 = ((const float4*)b1)[fblk];
    float4 bb2 = ((const float4*)b2)[fblk];
    float4* tilev = (float4*)tile;

    int ngroups = (N + TN - 1) / TN;
    for (int g = blockIdx.x; g < ngroups; g += gridDim.x) {
        int base = g * TN;
        __syncthreads();   // previous iteration's tile reads complete (also covers weight load, 1st iter)

        // stage agg tile [TN][HF]
        for (int i = tid; i < TN * (HF / 4); i += 512) {
            int node = base + (i >> 5);
            float4 val = make_float4(0.f, 0.f, 0.f, 0.f);
            if (node < N) val = ((const float4*)data)[(size_t)node * (HF / 4) + (i & 31)];
            tilev[i] = val;
        }
        __syncthreads();

        // pass A: h = ssp(agg @ w1 + b1), two nodes per thread
        float4 a0 = bb1, a1 = bb1;
        #pragma unroll 8
        for (int k = 0; k < HF; ++k) {
            float  x0 = tile[nl][k];
            float  x1 = tile[nl + 16][k];
            float4 w  = w1sv[k * 32 + fblk];
            fma4(a0, x0, w);
            fma4(a1, x1, w);
        }
        a0.x = ssp(a0.x); a0.y = ssp(a0.y); a0.z = ssp(a0.z); a0.w = ssp(a0.w);
        a1.x = ssp(a1.x); a1.y = ssp(a1.y); a1.z = ssp(a1.z); a1.w = ssp(a1.w);

        __syncthreads();   // all tile reads of pass A done
        tilev[nl * 32 + fblk]        = a0;   // overwrite tile with h
        tilev[(nl + 16) * 32 + fblk] = a1;
        __syncthreads();

        // pass B: out = v + h @ w2 + b2
        float4 c0 = bb2, c1 = bb2;
        #pragma unroll 8
        for (int k = 0; k < HF; ++k) {
            float  x0 = tile[nl][k];
            float  x1 = tile[nl + 16][k];
            float4 w  = w2sv[k * 32 + fblk];
            fma4(c0, x0, w);
            fma4(c1, x1, w);
        }
        int n0 = base + nl, n1 = base + nl + 16;
        if (n0 < N) {
            float4 vv = ((const float4*)v)[(size_t)n0 * 32 + fblk];
            c0.x += vv.x; c0.y += vv.y; c0.z += vv.z; c0.w += vv.w;
            ((float4*)data)[(size_t)n0 * 32 + fblk] = c0;
        }
        if (n1 < N) {
            float4 vv = ((const float4*)v)[(size_t)n1 * 32 + fblk];
            c1.x += vv.x; c1.y += vv.y; c1.z += vv.z; c1.w += vv.w;
            ((float4*)data)[(size_t)n1 * 32 + fblk] = c1;
        }
    }
}

extern "C" void kernel_launch(void* const* d_in, const int* in_sizes, int n_in,
                              void* d_out, int out_size, void* d_ws, size_t ws_size,
                              hipStream_t stream) {
    const float* v  = (const float*)d_in[0];
    const float* e  = (const float*)d_in[1];
    const int*   ei = (const int*)d_in[2];
    const float* w1 = (const float*)d_in[3];
    const float* b1 = (const float*)d_in[4];
    const float* w2 = (const float*)d_in[5];
    const float* b2 = (const float*)d_in[6];
    float* out = (float*)d_out;

    int N = in_sizes[0] / HF;    // 50000
    int E = in_sizes[2] / 2;     // 600000
    const int* tgt = ei + E;     // edge_index[1] = target node per edge

    // zero the accumulator (d_out doubles as agg buffer)
    hipMemsetAsync(out, 0, (size_t)N * HF * sizeof(float), stream);

    // scatter-add
    long long total_t = (long long)E * 32;
    int blocks = (int)((total_t + 255) / 256);
    scatter_add_kernel<<<blocks, 256, 0, stream>>>(e, tgt, out, E);

    // fused MLP + residual, in place
    mlp_kernel<<<512, 512, 0, stream>>>(out, v, w1, b1, w2, b2, N);
}

// Round 2
// 333.277 us; speedup vs baseline: 3.4548x; 3.4548x over previous
//
#include <hip/hip_runtime.h>
#include <math.h>

#define HF 128   // feature width
#define TN 32    // nodes per tile in the MLP kernel

// ---------------------------------------------------------------------------
// CSR build: histogram -> exclusive scan -> bucket fill
// ---------------------------------------------------------------------------
__global__ void hist_kernel(const int* __restrict__ tgt, int* __restrict__ counts, int E) {
    int eid = blockIdx.x * blockDim.x + threadIdx.x;
    if (eid < E) atomicAdd(&counts[tgt[eid]], 1);
}

__global__ __launch_bounds__(1024) void scan_kernel(const int* __restrict__ counts,
                                                    int* __restrict__ offsets, int N) {
    // exclusive scan of counts[0..N) into offsets[0..N], offsets[N] = total
    __shared__ int wsums[16];
    __shared__ int running_s;
    int tid = threadIdx.x;
    int lane = tid & 63, wave = tid >> 6;
    if (tid == 0) running_s = 0;
    __syncthreads();
    int nchunks = (N + 1023) / 1024;
    for (int c = 0; c < nchunks; ++c) {
        int i = c * 1024 + tid;
        int val = (i < N) ? counts[i] : 0;
        int x = val;
        #pragma unroll
        for (int d = 1; d < 64; d <<= 1) {
            int y = __shfl_up(x, d, 64);
            if (lane >= d) x += y;
        }
        if (lane == 63) wsums[wave] = x;
        __syncthreads();
        if (wave == 0) {
            int s = (lane < 16) ? wsums[lane] : 0;
            #pragma unroll
            for (int d = 1; d < 16; d <<= 1) {
                int y = __shfl_up(s, d, 64);
                if (lane >= d) s += y;
            }
            if (lane < 16) wsums[lane] = s;
        }
        __syncthreads();
        int running = running_s;
        int wprefix = (wave > 0) ? wsums[wave - 1] : 0;
        if (i < N) offsets[i] = running + wprefix + (x - val);
        int total = wsums[15];
        __syncthreads();                    // everyone has read running_s / wsums
        if (tid == 0) running_s = running + total;
        __syncthreads();
    }
    if (tid == 0) offsets[N] = running_s;
}

__global__ void fill_kernel(const int* __restrict__ tgt, const int* __restrict__ offsets,
                            int* __restrict__ cursor, int* __restrict__ edge_list, int E) {
    int eid = blockIdx.x * blockDim.x + threadIdx.x;
    if (eid >= E) return;
    int t = tgt[eid];
    int pos = atomicAdd(&cursor[t], 1);
    edge_list[offsets[t] + pos] = eid;
}

// ---------------------------------------------------------------------------
// Gather-sum: one wave per node, float2 per lane, 2-way unrolled for ILP.
// Writes every agg row (zero for empty buckets) -> no output memset needed.
// ---------------------------------------------------------------------------
__global__ __launch_bounds__(256) void gather_kernel(const float* __restrict__ e,
                                                     const int* __restrict__ edge_list,
                                                     const int* __restrict__ offsets,
                                                     float* __restrict__ agg, int N) {
    int wid = (blockIdx.x * blockDim.x + threadIdx.x) >> 6;   // node id
    if (wid >= N) return;
    int lane = threadIdx.x & 63;
    int beg = offsets[wid], end = offsets[wid + 1];
    float2 acc0 = make_float2(0.f, 0.f), acc1 = make_float2(0.f, 0.f);
    int j = beg;
    for (; j + 1 < end; j += 2) {
        int e0 = edge_list[j], e1 = edge_list[j + 1];
        float2 v0 = ((const float2*)(e + (size_t)e0 * HF))[lane];
        float2 v1 = ((const float2*)(e + (size_t)e1 * HF))[lane];
        acc0.x += v0.x; acc0.y += v0.y;
        acc1.x += v1.x; acc1.y += v1.y;
    }
    if (j < end) {
        int e0 = edge_list[j];
        float2 v0 = ((const float2*)(e + (size_t)e0 * HF))[lane];
        acc0.x += v0.x; acc0.y += v0.y;
    }
    acc0.x += acc1.x; acc0.y += acc1.y;
    ((float2*)(agg + (size_t)wid * HF))[lane] = acc0;
}

// ---------------------------------------------------------------------------
// Fallback scatter (old path) if ws_size is too small for CSR
// ---------------------------------------------------------------------------
__global__ void scatter_add_kernel(const float* __restrict__ e,
                                   const int* __restrict__ tgt,
                                   float* __restrict__ agg, int E) {
    int t = blockIdx.x * blockDim.x + threadIdx.x;
    int eid = t >> 5;
    if (eid >= E) return;
    int c = t & 31;
    int dst = tgt[eid];
    float4 val = *reinterpret_cast<const float4*>(e + (size_t)eid * HF + c * 4);
    float* p = agg + (size_t)dst * HF + c * 4;
    unsafeAtomicAdd(p + 0, val.x);
    unsafeAtomicAdd(p + 1, val.y);
    unsafeAtomicAdd(p + 2, val.z);
    unsafeAtomicAdd(p + 3, val.w);
}

// ---------------------------------------------------------------------------
// Phase 2: out = v + ( ssp(agg @ w1 + b1) @ w2 + b2 ), in place over agg rows.
// ---------------------------------------------------------------------------
__device__ __forceinline__ float ssp(float x) {
    const float SHIFT = 0.69314718055994531f;
    return (x > 0.f) ? (x + log1pf(expf(-x)) - SHIFT)
                     : (log1pf(expf(x)) - SHIFT);
}

__device__ __forceinline__ void fma4(float4& acc, float a, const float4& w) {
    acc.x = fmaf(a, w.x, acc.x);
    acc.y = fmaf(a, w.y, acc.y);
    acc.z = fmaf(a, w.z, acc.z);
    acc.w = fmaf(a, w.w, acc.w);
}

__global__ __launch_bounds__(512) void mlp_kernel(
        float* __restrict__ data,       // agg in, final output out (in place; row-disjoint per block)
        const float* __restrict__ v,
        const float* __restrict__ w1, const float* __restrict__ b1,
        const float* __restrict__ w2, const float* __restrict__ b2,
        int N) {
    __shared__ float w1s[HF * HF];
    __shared__ float w2s[HF * HF];
    __shared__ float tile[TN][HF];

    int tid = threadIdx.x;
    float4* w1sv = (float4*)w1s;
    float4* w2sv = (float4*)w2s;
    const float4* w1v = (const float4*)w1;
    const float4* w2v = (const float4*)w2;
    for (int i = tid; i < HF * HF / 4; i += 512) {
        w1sv[i] = w1v[i];
        w2sv[i] = w2v[i];
    }

    int nl   = tid >> 5;
    int fblk = tid & 31;
    float4 bb1 = ((const float4*)b1)[fblk];
    float4 bb2 = ((const float4*)b2)[fblk];
    float4* tilev = (float4*)tile;

    int ngroups = (N + TN - 1) / TN;
    for (int g = blockIdx.x; g < ngroups; g += gridDim.x) {
        int base = g * TN;
        __syncthreads();

        for (int i = tid; i < TN * (HF / 4); i += 512) {
            int node = base + (i >> 5);
            float4 val = make_float4(0.f, 0.f, 0.f, 0.f);
            if (node < N) val = ((const float4*)data)[(size_t)node * (HF / 4) + (i & 31)];
            tilev[i] = val;
        }
        __syncthreads();

        float4 a0 = bb1, a1 = bb1;
        #pragma unroll 8
        for (int k = 0; k < HF; ++k) {
            float  x0 = tile[nl][k];
            float  x1 = tile[nl + 16][k];
            float4 w  = w1sv[k * 32 + fblk];
            fma4(a0, x0, w);
            fma4(a1, x1, w);
        }
        a0.x = ssp(a0.x); a0.y = ssp(a0.y); a0.z = ssp(a0.z); a0.w = ssp(a0.w);
        a1.x = ssp(a1.x); a1.y = ssp(a1.y); a1.z = ssp(a1.z); a1.w = ssp(a1.w);

        __syncthreads();
        tilev[nl * 32 + fblk]        = a0;
        tilev[(nl + 16) * 32 + fblk] = a1;
        __syncthreads();

        float4 c0 = bb2, c1 = bb2;
        #pragma unroll 8
        for (int k = 0; k < HF; ++k) {
            float  x0 = tile[nl][k];
            float  x1 = tile[nl + 16][k];
            float4 w  = w2sv[k * 32 + fblk];
            fma4(c0, x0, w);
            fma4(c1, x1, w);
        }
        int n0 = base + nl, n1 = base + nl + 16;
        if (n0 < N) {
            float4 vv = ((const float4*)v)[(size_t)n0 * 32 + fblk];
            c0.x += vv.x; c0.y += vv.y; c0.z += vv.z; c0.w += vv.w;
            ((float4*)data)[(size_t)n0 * 32 + fblk] = c0;
        }
        if (n1 < N) {
            float4 vv = ((const float4*)v)[(size_t)n1 * 32 + fblk];
            c1.x += vv.x; c1.y += vv.y; c1.z += vv.z; c1.w += vv.w;
            ((float4*)data)[(size_t)n1 * 32 + fblk] = c1;
        }
    }
}

extern "C" void kernel_launch(void* const* d_in, const int* in_sizes, int n_in,
                              void* d_out, int out_size, void* d_ws, size_t ws_size,
                              hipStream_t stream) {
    const float* v  = (const float*)d_in[0];
    const float* e  = (const float*)d_in[1];
    const int*   ei = (const int*)d_in[2];
    const float* w1 = (const float*)d_in[3];
    const float* b1 = (const float*)d_in[4];
    const float* w2 = (const float*)d_in[5];
    const float* b2 = (const float*)d_in[6];
    float* out = (float*)d_out;

    int N = in_sizes[0] / HF;    // 50000
    int E = in_sizes[2] / 2;     // 600000
    const int* tgt = ei + E;     // edge_index[1] = target node per edge

    size_t needed = ((size_t)3 * N + 16 + (size_t)E) * sizeof(int);
    if (ws_size >= needed) {
        // ---- CSR path ----
        int* counts    = (int*)d_ws;          // N
        int* offsets   = counts + N;          // N+1
        int* cursor    = offsets + N + 1;     // N
        int* edge_list = cursor + N;          // E

        hipMemsetAsync(counts, 0, (size_t)N * sizeof(int), stream);
        hipMemsetAsync(cursor, 0, (size_t)N * sizeof(int), stream);

        int eb = (E + 255) / 256;
        hist_kernel<<<eb, 256, 0, stream>>>(tgt, counts, E);
        scan_kernel<<<1, 1024, 0, stream>>>(counts, offsets, N);
        fill_kernel<<<eb, 256, 0, stream>>>(tgt, offsets, cursor, edge_list, E);

        int nb = (N + 3) / 4;                 // 4 waves (nodes) per 256-thread block
        gather_kernel<<<nb, 256, 0, stream>>>(e, edge_list, offsets, out, N);
    } else {
        // ---- fallback: atomic scatter ----
        hipMemsetAsync(out, 0, (size_t)N * HF * sizeof(float), stream);
        long long total_t = (long long)E * 32;
        int blocks = (int)((total_t + 255) / 256);
        scatter_add_kernel<<<blocks, 256, 0, stream>>>(e, tgt, out, E);
    }

    // fused MLP + residual, in place
    mlp_kernel<<<512, 512, 0, stream>>>(out, v, w1, b1, w2, b2, N);
}

// Round 3
// 234.538 us; speedup vs baseline: 4.9093x; 1.4210x over previous
//
#include <hip/hip_runtime.h>
#include <math.h>

#define HF 128
#define WPAD 136      // padded LDS row stride (bf16 elems): 272 B, 16B-multiple, 2-way banks only

typedef short bfrag __attribute__((ext_vector_type(8)));   // 8 bf16 (4 VGPRs) - MFMA A/B frag
typedef float facc  __attribute__((ext_vector_type(4)));   // 4 f32 - MFMA C/D frag

__device__ __forceinline__ unsigned short f2bf(float x) {
    unsigned int u = __float_as_uint(x);
    unsigned int r = (u + 0x7FFFu + ((u >> 16) & 1u)) >> 16;
    return (unsigned short)r;
}

__device__ __forceinline__ float ssp(float x) {
    const float SHIFT = 0.69314718055994531f;
    return (x > 0.f) ? (x + log1pf(expf(-x)) - SHIFT)
                     : (log1pf(expf(x)) - SHIFT);
}

// ---------------------------------------------------------------------------
// CSR build
// ---------------------------------------------------------------------------
__global__ void hist_kernel(const int* __restrict__ tgt, int* __restrict__ counts, int E) {
    int eid = blockIdx.x * blockDim.x + threadIdx.x;
    if (eid < E) atomicAdd(&counts[tgt[eid]], 1);
}

// block-local exclusive scan; bsum[b] = block total
__global__ __launch_bounds__(1024) void scan1_kernel(const int* __restrict__ counts,
                                                     int* __restrict__ offsets,
                                                     int* __restrict__ bsum, int N) {
    __shared__ int ws[16];
    int t = threadIdx.x;
    int i = blockIdx.x * 1024 + t;
    int lane = t & 63, wv = t >> 6;
    int val = (i < N) ? counts[i] : 0;
    int x = val;
    #pragma unroll
    for (int d = 1; d < 64; d <<= 1) {
        int y = __shfl_up(x, d, 64);
        if (lane >= d) x += y;
    }
    if (lane == 63) ws[wv] = x;
    __syncthreads();
    if (wv == 0) {
        int s = (lane < 16) ? ws[lane] : 0;
        #pragma unroll
        for (int d = 1; d < 16; d <<= 1) {
            int y = __shfl_up(s, d, 64);
            if (lane >= d) s += y;
        }
        if (lane < 16) ws[lane] = s;
    }
    __syncthreads();
    int pre = ((wv > 0) ? ws[wv - 1] : 0) + (x - val);
    if (i < N) offsets[i] = pre;
    if (t == 0 && bsum) bsum[blockIdx.x] = ws[15];
}

// exclusive scan of block sums (nb <= 64, one wave)
__global__ void scan2_kernel(const int* __restrict__ bsum, int* __restrict__ bpre, int nb) {
    int lane = threadIdx.x & 63;
    int v = (lane < nb) ? bsum[lane] : 0;
    int x = v;
    #pragma unroll
    for (int d = 1; d < 64; d <<= 1) {
        int y = __shfl_up(x, d, 64);
        if (lane >= d) x += y;
    }
    if (lane < nb) bpre[lane] = x - v;
}

__global__ __launch_bounds__(1024) void scan3_kernel(int* __restrict__ offsets,
                                                     const int* __restrict__ bpre, int N, int E) {
    int i = blockIdx.x * 1024 + threadIdx.x;
    if (i < N) offsets[i] += bpre[blockIdx.x];
    if (blockIdx.x == 0 && threadIdx.x == 0) offsets[N] = E;
}

// counts doubles as cursor: atomicSub yields a unique slot in [0, count)
__global__ void fill_kernel(const int* __restrict__ tgt, const int* __restrict__ offsets,
                            int* __restrict__ counts, int* __restrict__ edge_list, int E) {
    int eid = blockIdx.x * blockDim.x + threadIdx.x;
    if (eid >= E) return;
    int t = tgt[eid];
    int pos = atomicSub(&counts[t], 1) - 1;
    edge_list[offsets[t] + pos] = eid;
}

// ---------------------------------------------------------------------------
// Gather-sum into bf16 agg: one wave per node, float4/lane, 2 edges per iter
// ---------------------------------------------------------------------------
__global__ __launch_bounds__(256) void gather_kernel(const float* __restrict__ e,
                                                     const int* __restrict__ edge_list,
                                                     const int* __restrict__ offsets,
                                                     unsigned short* __restrict__ aggb, int N) {
    int wid = (blockIdx.x * blockDim.x + threadIdx.x) >> 6;
    if (wid >= N) return;
    int lane  = threadIdx.x & 63;
    int half  = lane >> 5;     // which edge of the pair
    int chunk = lane & 31;     // float4 chunk within the 128-wide row
    int beg = offsets[wid], end = offsets[wid + 1];
    float4 acc = make_float4(0.f, 0.f, 0.f, 0.f);
    for (int j = beg; j < end; j += 2) {
        int jj = j + half;
        if (jj < end) {
            int eid = edge_list[jj];
            float4 vv = ((const float4*)(e + (size_t)eid * HF))[chunk];
            acc.x += vv.x; acc.y += vv.y; acc.z += vv.z; acc.w += vv.w;
        }
    }
    acc.x += __shfl_down(acc.x, 32, 64);
    acc.y += __shfl_down(acc.y, 32, 64);
    acc.z += __shfl_down(acc.z, 32, 64);
    acc.w += __shfl_down(acc.w, 32, 64);
    if (lane < 32) {
        ushort4 o;
        o.x = f2bf(acc.x); o.y = f2bf(acc.y); o.z = f2bf(acc.z); o.w = f2bf(acc.w);
        ((ushort4*)(aggb + (size_t)wid * HF))[chunk] = o;
    }
}

// ---------------------------------------------------------------------------
// MFMA MLP: out = v + ( ssp(agg @ w1 + b1) @ w2 + b2 )
// 512 thr (8 waves), 128-node tiles. wave w: rows (w&3)*32 (two 16-row
// subtiles), cols (w>>2)*64 (four 16-col subtiles). 16x16x32 bf16 MFMA.
// A-frag: row=lane&15, k = 8*(lane>>4)+i. B-frag: col=lane&15 (from WT),
// same k. C/D: col=lane&15, row=4*(lane>>4)+i  [guide m89].
// ---------------------------------------------------------------------------
__global__ __launch_bounds__(512) void mlp_mfma_kernel(
        const unsigned short* __restrict__ aggb,
        const float* __restrict__ v,
        const float* __restrict__ w1, const float* __restrict__ b1,
        const float* __restrict__ w2, const float* __restrict__ b2,
        float* __restrict__ out, int N, int ngroups) {
    __shared__ unsigned short wt1[HF * WPAD];    // w1 transposed: wt1[n][k], 34 KB
    __shared__ unsigned short wt2[HF * WPAD];    // 34 KB
    __shared__ unsigned short atile[HF * WPAD];  // agg tile, reused for h tile (34 KB)

    int tid = threadIdx.x;
    // stage transposed bf16 weights (once per block)
    for (int idx = tid; idx < HF * HF; idx += 512) {
        int k = idx >> 7, n = idx & 127;
        wt1[n * WPAD + k] = f2bf(w1[idx]);
        wt2[n * WPAD + k] = f2bf(w2[idx]);
    }

    int w = tid >> 6, lane = tid & 63;
    int wr = (w & 3) * 32;     // row block base
    int wc = (w >> 1) & ~1 ? 0 : 0; (void)wc;
    int wchalf = (w >> 2) * 64;  // col half base
    int lr = lane & 15;
    int kg = lane >> 4;          // k-group 0..3
    float bias1[4], bias2[4];
    #pragma unroll
    for (int nt = 0; nt < 4; ++nt) {
        int col = wchalf + nt * 16 + lr;
        bias1[nt] = b1[col];
        bias2[nt] = b2[col];
    }

    for (int g = blockIdx.x; g < ngroups; g += gridDim.x) {
        int base = g * HF;
        __syncthreads();   // previous iteration's tile reads done

        // stage agg tile (bf16 straight copy, zero tail rows)
        for (int idx = tid; idx < HF * 16; idx += 512) {
            int r = idx >> 4, c = idx & 15;
            int row = base + r;
            bfrag val = {0,0,0,0,0,0,0,0};
            if (row < N) val = *(const bfrag*)(aggb + (size_t)row * HF + c * 8);
            *(bfrag*)(atile + r * WPAD + c * 8) = val;
        }
        __syncthreads();

        // pass A: h = ssp(agg @ w1 + b1)
        facc acc[2][4];
        #pragma unroll
        for (int m = 0; m < 2; ++m)
            #pragma unroll
            for (int nt = 0; nt < 4; ++nt)
                acc[m][nt] = (facc){0.f, 0.f, 0.f, 0.f};
        #pragma unroll
        for (int ks = 0; ks < 4; ++ks) {
            int k0 = ks * 32 + kg * 8;
            bfrag a0 = *(const bfrag*)(atile + (wr + lr) * WPAD + k0);
            bfrag a1 = *(const bfrag*)(atile + (wr + 16 + lr) * WPAD + k0);
            #pragma unroll
            for (int nt = 0; nt < 4; ++nt) {
                bfrag b = *(const bfrag*)(wt1 + (wchalf + nt * 16 + lr) * WPAD + k0);
                acc[0][nt] = __builtin_amdgcn_mfma_f32_16x16x32_bf16(a0, b, acc[0][nt], 0, 0, 0);
                acc[1][nt] = __builtin_amdgcn_mfma_f32_16x16x32_bf16(a1, b, acc[1][nt], 0, 0, 0);
            }
        }
        __syncthreads();   // atile reads done, safe to overwrite with h

        #pragma unroll
        for (int m = 0; m < 2; ++m) {
            int rbase = wr + m * 16 + kg * 4;
            #pragma unroll
            for (int nt = 0; nt < 4; ++nt) {
                int col = wchalf + nt * 16 + lr;
                #pragma unroll
                for (int i = 0; i < 4; ++i) {
                    float h = ssp(acc[m][nt][i] + bias1[nt]);
                    atile[(rbase + i) * WPAD + col] = f2bf(h);
                }
            }
        }
        __syncthreads();

        // pass B: out = v + h @ w2 + b2
        facc acc2[2][4];
        #pragma unroll
        for (int m = 0; m < 2; ++m)
            #pragma unroll
            for (int nt = 0; nt < 4; ++nt)
                acc2[m][nt] = (facc){0.f, 0.f, 0.f, 0.f};
        #pragma unroll
        for (int ks = 0; ks < 4; ++ks) {
            int k0 = ks * 32 + kg * 8;
            bfrag a0 = *(const bfrag*)(atile + (wr + lr) * WPAD + k0);
            bfrag a1 = *(const bfrag*)(atile + (wr + 16 + lr) * WPAD + k0);
            #pragma unroll
            for (int nt = 0; nt < 4; ++nt) {
                bfrag b = *(const bfrag*)(wt2 + (wchalf + nt * 16 + lr) * WPAD + k0);
                acc2[0][nt] = __builtin_amdgcn_mfma_f32_16x16x32_bf16(a0, b, acc2[0][nt], 0, 0, 0);
                acc2[1][nt] = __builtin_amdgcn_mfma_f32_16x16x32_bf16(a1, b, acc2[1][nt], 0, 0, 0);
            }
        }

        #pragma unroll
        for (int m = 0; m < 2; ++m) {
            #pragma unroll
            for (int i = 0; i < 4; ++i) {
                int row = base + wr + m * 16 + kg * 4 + i;
                if (row < N) {
                    #pragma unroll
                    for (int nt = 0; nt < 4; ++nt) {
                        int col = wchalf + nt * 16 + lr;
                        out[(size_t)row * HF + col] = acc2[m][nt][i] + bias2[nt] + v[(size_t)row * HF + col];
                    }
                }
            }
        }
    }
}

// ---------------------------------------------------------------------------
// Fallback path (ws too small): atomic scatter + f32 vector MLP (round-1 code)
// ---------------------------------------------------------------------------
__global__ void scatter_add_kernel(const float* __restrict__ e,
                                   const int* __restrict__ tgt,
                                   float* __restrict__ agg, int E) {
    int t = blockIdx.x * blockDim.x + threadIdx.x;
    int eid = t >> 5;
    if (eid >= E) return;
    int c = t & 31;
    int dst = tgt[eid];
    float4 val = *reinterpret_cast<const float4*>(e + (size_t)eid * HF + c * 4);
    float* p = agg + (size_t)dst * HF + c * 4;
    unsafeAtomicAdd(p + 0, val.x);
    unsafeAtomicAdd(p + 1, val.y);
    unsafeAtomicAdd(p + 2, val.z);
    unsafeAtomicAdd(p + 3, val.w);
}

__device__ __forceinline__ void fma4(float4& acc, float a, const float4& w) {
    acc.x = fmaf(a, w.x, acc.x);
    acc.y = fmaf(a, w.y, acc.y);
    acc.z = fmaf(a, w.z, acc.z);
    acc.w = fmaf(a, w.w, acc.w);
}

__global__ __launch_bounds__(512) void mlp_kernel(
        float* __restrict__ data, const float* __restrict__ v,
        const float* __restrict__ w1, const float* __restrict__ b1,
        const float* __restrict__ w2, const float* __restrict__ b2, int N) {
    __shared__ float w1s[HF * HF];
    __shared__ float w2s[HF * HF];
    __shared__ float tile[32][HF];
    int tid = threadIdx.x;
    float4* w1sv = (float4*)w1s; float4* w2sv = (float4*)w2s;
    for (int i = tid; i < HF * HF / 4; i += 512) {
        w1sv[i] = ((const float4*)w1)[i];
        w2sv[i] = ((const float4*)w2)[i];
    }
    int nl = tid >> 5, fblk = tid & 31;
    float4 bb1 = ((const float4*)b1)[fblk];
    float4 bb2 = ((const float4*)b2)[fblk];
    float4* tilev = (float4*)tile;
    int ngroups = (N + 31) / 32;
    for (int g = blockIdx.x; g < ngroups; g += gridDim.x) {
        int base = g * 32;
        __syncthreads();
        for (int i = tid; i < 32 * (HF / 4); i += 512) {
            int node = base + (i >> 5);
            float4 val = make_float4(0.f, 0.f, 0.f, 0.f);
            if (node < N) val = ((const float4*)data)[(size_t)node * (HF / 4) + (i & 31)];
            tilev[i] = val;
        }
        __syncthreads();
        float4 a0 = bb1, a1 = bb1;
        #pragma unroll 8
        for (int k = 0; k < HF; ++k) {
            float x0 = tile[nl][k], x1 = tile[nl + 16][k];
            float4 w = w1sv[k * 32 + fblk];
            fma4(a0, x0, w); fma4(a1, x1, w);
        }
        a0.x = ssp(a0.x); a0.y = ssp(a0.y); a0.z = ssp(a0.z); a0.w = ssp(a0.w);
        a1.x = ssp(a1.x); a1.y = ssp(a1.y); a1.z = ssp(a1.z); a1.w = ssp(a1.w);
        __syncthreads();
        tilev[nl * 32 + fblk] = a0;
        tilev[(nl + 16) * 32 + fblk] = a1;
        __syncthreads();
        float4 c0 = bb2, c1 = bb2;
        #pragma unroll 8
        for (int k = 0; k < HF; ++k) {
            float x0 = tile[nl][k], x1 = tile[nl + 16][k];
            float4 w = w2sv[k * 32 + fblk];
            fma4(c0, x0, w); fma4(c1, x1, w);
        }
        int n0 = base + nl, n1 = base + nl + 16;
        if (n0 < N) {
            float4 vv = ((const float4*)v)[(size_t)n0 * 32 + fblk];
            c0.x += vv.x; c0.y += vv.y; c0.z += vv.z; c0.w += vv.w;
            ((float4*)data)[(size_t)n0 * 32 + fblk] = c0;
        }
        if (n1 < N) {
            float4 vv = ((const float4*)v)[(size_t)n1 * 32 + fblk];
            c1.x += vv.x; c1.y += vv.y; c1.z += vv.z; c1.w += vv.w;
            ((float4*)data)[(size_t)n1 * 32 + fblk] = c1;
        }
    }
}

extern "C" void kernel_launch(void* const* d_in, const int* in_sizes, int n_in,
                              void* d_out, int out_size, void* d_ws, size_t ws_size,
                              hipStream_t stream) {
    const float* v  = (const float*)d_in[0];
    const float* e  = (const float*)d_in[1];
    const int*   ei = (const int*)d_in[2];
    const float* w1 = (const float*)d_in[3];
    const float* b1 = (const float*)d_in[4];
    const float* w2 = (const float*)d_in[5];
    const float* b2 = (const float*)d_in[6];
    float* out = (float*)d_out;

    int N = in_sizes[0] / HF;    // 50000
    int E = in_sizes[2] / 2;     // 600000
    const int* tgt = ei + E;     // edge_index[1]

    // ws layout: counts[N] | offsets[N+1] | bsum[64] | bpre[64] | edge_list[E] | aggb[N*HF bf16]
    size_t ints = (size_t)N + (N + 1) + 64 + 64 + E;
    size_t needed = ints * 4 + 16 + (size_t)N * HF * 2;
    if (ws_size >= needed) {
        int* counts    = (int*)d_ws;
        int* offsets   = counts + N;
        int* bsum      = offsets + N + 1;
        int* bpre      = bsum + 64;
        int* edge_list = bpre + 64;
        uintptr_t p = (uintptr_t)(edge_list + E);
        p = (p + 15) & ~(uintptr_t)15;
        unsigned short* aggb = (unsigned short*)p;

        hipMemsetAsync(counts, 0, (size_t)N * sizeof(int), stream);

        int eb = (E + 255) / 256;
        int nb = (N + 1023) / 1024;   // 49
        hist_kernel<<<eb, 256, 0, stream>>>(tgt, counts, E);
        scan1_kernel<<<nb, 1024, 0, stream>>>(counts, offsets, bsum, N);
        scan2_kernel<<<1, 64, 0, stream>>>(bsum, bpre, nb);
        scan3_kernel<<<nb, 1024, 0, stream>>>(offsets, bpre, N, E);
        fill_kernel<<<eb, 256, 0, stream>>>(tgt, offsets, counts, edge_list, E);

        gather_kernel<<<(N + 3) / 4, 256, 0, stream>>>(e, edge_list, offsets, aggb, N);

        int ngroups = (N + HF - 1) / HF;  // 391
        mlp_mfma_kernel<<<256, 512, 0, stream>>>(aggb, v, w1, b1, w2, b2, out, N, ngroups);
    } else {
        hipMemsetAsync(out, 0, (size_t)N * HF * sizeof(float), stream);
        long long total_t = (long long)E * 32;
        scatter_add_kernel<<<(int)((total_t + 255) / 256), 256, 0, stream>>>(e, tgt, out, E);
        mlp_kernel<<<512, 512, 0, stream>>>(out, v, w1, b1, w2, b2, N);
    }
}

// Round 4
// 210.269 us; speedup vs baseline: 5.4759x; 1.1154x over previous
//
#include <hip/hip_runtime.h>
#include <math.h>

#define HF 128
#define WPAD 136      // padded LDS row stride (bf16 elems): 272 B = 16B-multiple, 2-way banks only (free)

typedef short bfrag __attribute__((ext_vector_type(8)));   // 8 bf16 (4 VGPRs) - MFMA A/B frag
typedef float facc  __attribute__((ext_vector_type(4)));   // 4 f32 - MFMA C/D frag
typedef float f4v   __attribute__((ext_vector_type(4)));   // vector float4 (for nontemporal builtins)

__device__ __forceinline__ unsigned short f2bf(float x) {
    unsigned int u = __float_as_uint(x);
    unsigned int r = (u + 0x7FFFu + ((u >> 16) & 1u)) >> 16;
    return (unsigned short)r;
}

__device__ __forceinline__ float ssp(float x) {
    const float SHIFT = 0.69314718055994531f;
    return (x > 0.f) ? (x + log1pf(expf(-x)) - SHIFT)
                     : (log1pf(expf(x)) - SHIFT);
}

// ---------------------------------------------------------------------------
// CSR build
// ---------------------------------------------------------------------------
__global__ void hist_kernel(const int* __restrict__ tgt, int* __restrict__ counts, int E) {
    int eid = blockIdx.x * blockDim.x + threadIdx.x;
    if (eid < E) atomicAdd(&counts[tgt[eid]], 1);
}

// block-local exclusive scan; bsum[b] = block total
__global__ __launch_bounds__(1024) void scan1_kernel(const int* __restrict__ counts,
                                                     int* __restrict__ offsets,
                                                     int* __restrict__ bsum, int N) {
    __shared__ int ws[16];
    int t = threadIdx.x;
    int i = blockIdx.x * 1024 + t;
    int lane = t & 63, wv = t >> 6;
    int val = (i < N) ? counts[i] : 0;
    int x = val;
    #pragma unroll
    for (int d = 1; d < 64; d <<= 1) {
        int y = __shfl_up(x, d, 64);
        if (lane >= d) x += y;
    }
    if (lane == 63) ws[wv] = x;
    __syncthreads();
    if (wv == 0) {
        int s = (lane < 16) ? ws[lane] : 0;
        #pragma unroll
        for (int d = 1; d < 16; d <<= 1) {
            int y = __shfl_up(s, d, 64);
            if (lane >= d) s += y;
        }
        if (lane < 16) ws[lane] = s;
    }
    __syncthreads();
    int pre = ((wv > 0) ? ws[wv - 1] : 0) + (x - val);
    if (i < N) offsets[i] = pre;
    if (t == 0) bsum[blockIdx.x] = ws[15];
}

// fused: block b adds exclusive-prefix of bsum[0..b) (recomputed by wave 0), sets offsets[N]
__global__ __launch_bounds__(1024) void scan23_kernel(int* __restrict__ offsets,
                                                      const int* __restrict__ bsum,
                                                      int N, int E, int nb) {
    __shared__ int pre_s;
    int t = threadIdx.x;
    if (t < 64) {
        int v = (t < nb && t < (int)blockIdx.x) ? bsum[t] : 0;
        #pragma unroll
        for (int d = 32; d > 0; d >>= 1) v += __shfl_down(v, d, 64);
        if (t == 0) pre_s = v;
    }
    __syncthreads();
    int i = blockIdx.x * 1024 + t;
    if (i < N) offsets[i] += pre_s;
    if (blockIdx.x == 0 && t == 0) offsets[N] = E;
}

// counts doubles as cursor: atomicSub yields a unique slot in [0, count)
__global__ void fill_kernel(const int* __restrict__ tgt, const int* __restrict__ offsets,
                            int* __restrict__ counts, int* __restrict__ edge_list, int E) {
    int eid = blockIdx.x * blockDim.x + threadIdx.x;
    if (eid >= E) return;
    int t = tgt[eid];
    int pos = atomicSub(&counts[t], 1) - 1;
    edge_list[offsets[t] + pos] = eid;
}

// ---------------------------------------------------------------------------
// Gather-sum into bf16 agg: one wave per node, float4/lane, 4 edges in flight
// (2 per lane-half), nontemporal loads of e (read-once stream).
// ---------------------------------------------------------------------------
__global__ __launch_bounds__(256) void gather_kernel(const float* __restrict__ e,
                                                     const int* __restrict__ edge_list,
                                                     const int* __restrict__ offsets,
                                                     unsigned short* __restrict__ aggb, int N) {
    int wid = (blockIdx.x * blockDim.x + threadIdx.x) >> 6;
    if (wid >= N) return;
    int lane  = threadIdx.x & 63;
    int half  = lane >> 5;     // which edge of a pair
    int chunk = lane & 31;     // float4 chunk within the 128-wide row
    int beg = offsets[wid], end = offsets[wid + 1];
    f4v acc0 = {0.f, 0.f, 0.f, 0.f};
    f4v acc1 = {0.f, 0.f, 0.f, 0.f};
    int j = beg;
    // main: 4 edges per iteration, loads issued before any use
    for (; j + 4 <= end; j += 4) {
        int ea = edge_list[j + half];
        int eb = edge_list[j + 2 + half];
        f4v ra = __builtin_nontemporal_load((const f4v*)(e + (size_t)ea * HF) + chunk);
        f4v rb = __builtin_nontemporal_load((const f4v*)(e + (size_t)eb * HF) + chunk);
        acc0 += ra;
        acc1 += rb;
    }
    // tail: 0..3 edges
    for (; j < end; j += 2) {
        int jj = j + half;
        if (jj < end) {
            int ec = edge_list[jj];
            f4v rc = __builtin_nontemporal_load((const f4v*)(e + (size_t)ec * HF) + chunk);
            acc0 += rc;
        }
    }
    acc0 += acc1;
    acc0.x += __shfl_down(acc0.x, 32, 64);
    acc0.y += __shfl_down(acc0.y, 32, 64);
    acc0.z += __shfl_down(acc0.z, 32, 64);
    acc0.w += __shfl_down(acc0.w, 32, 64);
    if (lane < 32) {
        ushort4 o;
        o.x = f2bf(acc0.x); o.y = f2bf(acc0.y); o.z = f2bf(acc0.z); o.w = f2bf(acc0.w);
        ((ushort4*)(aggb + (size_t)wid * HF))[chunk] = o;
    }
}

// ---------------------------------------------------------------------------
// MFMA MLP: out = v + ( ssp(agg @ w1 + b1) @ w2 + b2 )
// 512 thr (8 waves), 128-node tiles. wave w: rows (w&3)*32, cols (w>>2)*64.
// 16x16x32 bf16 MFMA; C/D: col=lane&15, row=4*(lane>>4)+i  [guide m89].
// ---------------------------------------------------------------------------
__global__ __launch_bounds__(512) void mlp_mfma_kernel(
        const unsigned short* __restrict__ aggb,
        const float* __restrict__ v,
        const float* __restrict__ w1, const float* __restrict__ b1,
        const float* __restrict__ w2, const float* __restrict__ b2,
        float* __restrict__ out, int N, int ngroups) {
    __shared__ unsigned short wt1[HF * WPAD];    // w1 transposed: wt1[n][k], 34 KB
    __shared__ unsigned short wt2[HF * WPAD];    // 34 KB
    __shared__ unsigned short atile[HF * WPAD];  // agg tile, reused for h tile (34 KB)

    int tid = threadIdx.x;
    for (int idx = tid; idx < HF * HF; idx += 512) {
        int k = idx >> 7, n = idx & 127;
        wt1[n * WPAD + k] = f2bf(w1[idx]);
        wt2[n * WPAD + k] = f2bf(w2[idx]);
    }

    int w = tid >> 6, lane = tid & 63;
    int wr = (w & 3) * 32;       // row block base
    int wchalf = (w >> 2) * 64;  // col half base
    int lr = lane & 15;
    int kg = lane >> 4;          // k-group 0..3
    float bias1[4], bias2[4];
    #pragma unroll
    for (int nt = 0; nt < 4; ++nt) {
        int col = wchalf + nt * 16 + lr;
        bias1[nt] = b1[col];
        bias2[nt] = b2[col];
    }

    for (int g = blockIdx.x; g < ngroups; g += gridDim.x) {
        int base = g * HF;
        __syncthreads();   // previous iteration's tile reads done (covers weight staging, 1st iter)

        for (int idx = tid; idx < HF * 16; idx += 512) {
            int r = idx >> 4, c = idx & 15;
            int row = base + r;
            bfrag val = {0,0,0,0,0,0,0,0};
            if (row < N) val = *(const bfrag*)(aggb + (size_t)row * HF + c * 8);
            *(bfrag*)(atile + r * WPAD + c * 8) = val;
        }
        __syncthreads();

        // pass A: h = ssp(agg @ w1 + b1)
        facc acc[2][4];
        #pragma unroll
        for (int m = 0; m < 2; ++m)
            #pragma unroll
            for (int nt = 0; nt < 4; ++nt)
                acc[m][nt] = (facc){0.f, 0.f, 0.f, 0.f};
        #pragma unroll
        for (int ks = 0; ks < 4; ++ks) {
            int k0 = ks * 32 + kg * 8;
            bfrag a0 = *(const bfrag*)(atile + (wr + lr) * WPAD + k0);
            bfrag a1 = *(const bfrag*)(atile + (wr + 16 + lr) * WPAD + k0);
            #pragma unroll
            for (int nt = 0; nt < 4; ++nt) {
                bfrag b = *(const bfrag*)(wt1 + (wchalf + nt * 16 + lr) * WPAD + k0);
                acc[0][nt] = __builtin_amdgcn_mfma_f32_16x16x32_bf16(a0, b, acc[0][nt], 0, 0, 0);
                acc[1][nt] = __builtin_amdgcn_mfma_f32_16x16x32_bf16(a1, b, acc[1][nt], 0, 0, 0);
            }
        }
        __syncthreads();   // atile reads done, safe to overwrite with h

        #pragma unroll
        for (int m = 0; m < 2; ++m) {
            int rbase = wr + m * 16 + kg * 4;
            #pragma unroll
            for (int nt = 0; nt < 4; ++nt) {
                int col = wchalf + nt * 16 + lr;
                #pragma unroll
                for (int i = 0; i < 4; ++i) {
                    float h = ssp(acc[m][nt][i] + bias1[nt]);
                    atile[(rbase + i) * WPAD + col] = f2bf(h);
                }
            }
        }
        __syncthreads();

        // pass B: out = v + h @ w2 + b2
        facc acc2[2][4];
        #pragma unroll
        for (int m = 0; m < 2; ++m)
            #pragma unroll
            for (int nt = 0; nt < 4; ++nt)
                acc2[m][nt] = (facc){0.f, 0.f, 0.f, 0.f};
        #pragma unroll
        for (int ks = 0; ks < 4; ++ks) {
            int k0 = ks * 32 + kg * 8;
            bfrag a0 = *(const bfrag*)(atile + (wr + lr) * WPAD + k0);
            bfrag a1 = *(const bfrag*)(atile + (wr + 16 + lr) * WPAD + k0);
            #pragma unroll
            for (int nt = 0; nt < 4; ++nt) {
                bfrag b = *(const bfrag*)(wt2 + (wchalf + nt * 16 + lr) * WPAD + k0);
                acc2[0][nt] = __builtin_amdgcn_mfma_f32_16x16x32_bf16(a0, b, acc2[0][nt], 0, 0, 0);
                acc2[1][nt] = __builtin_amdgcn_mfma_f32_16x16x32_bf16(a1, b, acc2[1][nt], 0, 0, 0);
            }
        }

        #pragma unroll
        for (int m = 0; m < 2; ++m) {
            #pragma unroll
            for (int i = 0; i < 4; ++i) {
                int row = base + wr + m * 16 + kg * 4 + i;
                if (row < N) {
                    #pragma unroll
                    for (int nt = 0; nt < 4; ++nt) {
                        int col = wchalf + nt * 16 + lr;
                        out[(size_t)row * HF + col] = acc2[m][nt][i] + bias2[nt] + v[(size_t)row * HF + col];
                    }
                }
            }
        }
    }
}

// ---------------------------------------------------------------------------
// Fallback path (ws too small): atomic scatter + f32 vector MLP
// ---------------------------------------------------------------------------
__global__ void scatter_add_kernel(const float* __restrict__ e,
                                   const int* __restrict__ tgt,
                                   float* __restrict__ agg, int E) {
    int t = blockIdx.x * blockDim.x + threadIdx.x;
    int eid = t >> 5;
    if (eid >= E) return;
    int c = t & 31;
    int dst = tgt[eid];
    float4 val = *reinterpret_cast<const float4*>(e + (size_t)eid * HF + c * 4);
    float* p = agg + (size_t)dst * HF + c * 4;
    unsafeAtomicAdd(p + 0, val.x);
    unsafeAtomicAdd(p + 1, val.y);
    unsafeAtomicAdd(p + 2, val.z);
    unsafeAtomicAdd(p + 3, val.w);
}

__device__ __forceinline__ void fma4(float4& acc, float a, const float4& w) {
    acc.x = fmaf(a, w.x, acc.x);
    acc.y = fmaf(a, w.y, acc.y);
    acc.z = fmaf(a, w.z, acc.z);
    acc.w = fmaf(a, w.w, acc.w);
}

__global__ __launch_bounds__(512) void mlp_kernel(
        float* __restrict__ data, const float* __restrict__ v,
        const float* __restrict__ w1, const float* __restrict__ b1,
        const float* __restrict__ w2, const float* __restrict__ b2, int N) {
    __shared__ float w1s[HF * HF];
    __shared__ float w2s[HF * HF];
    __shared__ float tile[32][HF];
    int tid = threadIdx.x;
    float4* w1sv = (float4*)w1s; float4* w2sv = (float4*)w2s;
    for (int i = tid; i < HF * HF / 4; i += 512) {
        w1sv[i] = ((const float4*)w1)[i];
        w2sv[i] = ((const float4*)w2)[i];
    }
    int nl = tid >> 5, fblk = tid & 31;
    float4 bb1 = ((const float4*)b1)[fblk];
    float4 bb2 = ((const float4*)b2)[fblk];
    float4* tilev = (float4*)tile;
    int ngroups = (N + 31) / 32;
    for (int g = blockIdx.x; g < ngroups; g += gridDim.x) {
        int base = g * 32;
        __syncthreads();
        for (int i = tid; i < 32 * (HF / 4); i += 512) {
            int node = base + (i >> 5);
            float4 val = make_float4(0.f, 0.f, 0.f, 0.f);
            if (node < N) val = ((const float4*)data)[(size_t)node * (HF / 4) + (i & 31)];
            tilev[i] = val;
        }
        __syncthreads();
        float4 a0 = bb1, a1 = bb1;
        #pragma unroll 8
        for (int k = 0; k < HF; ++k) {
            float x0 = tile[nl][k], x1 = tile[nl + 16][k];
            float4 w = w1sv[k * 32 + fblk];
            fma4(a0, x0, w); fma4(a1, x1, w);
        }
        a0.x = ssp(a0.x); a0.y = ssp(a0.y); a0.z = ssp(a0.z); a0.w = ssp(a0.w);
        a1.x = ssp(a1.x); a1.y = ssp(a1.y); a1.z = ssp(a1.z); a1.w = ssp(a1.w);
        __syncthreads();
        tilev[nl * 32 + fblk] = a0;
        tilev[(nl + 16) * 32 + fblk] = a1;
        __syncthreads();
        float4 c0 = bb2, c1 = bb2;
        #pragma unroll 8
        for (int k = 0; k < HF; ++k) {
            float x0 = tile[nl][k], x1 = tile[nl + 16][k];
            float4 w = w2sv[k * 32 + fblk];
            fma4(c0, x0, w); fma4(c1, x1, w);
        }
        int n0 = base + nl, n1 = base + nl + 16;
        if (n0 < N) {
            float4 vv = ((const float4*)v)[(size_t)n0 * 32 + fblk];
            c0.x += vv.x; c0.y += vv.y; c0.z += vv.z; c0.w += vv.w;
            ((float4*)data)[(size_t)n0 * 32 + fblk] = c0;
        }
        if (n1 < N) {
            float4 vv = ((const float4*)v)[(size_t)n1 * 32 + fblk];
            c1.x += vv.x; c1.y += vv.y; c1.z += vv.z; c1.w += vv.w;
            ((float4*)data)[(size_t)n1 * 32 + fblk] = c1;
        }
    }
}

extern "C" void kernel_launch(void* const* d_in, const int* in_sizes, int n_in,
                              void* d_out, int out_size, void* d_ws, size_t ws_size,
                              hipStream_t stream) {
    const float* v  = (const float*)d_in[0];
    const float* e  = (const float*)d_in[1];
    const int*   ei = (const int*)d_in[2];
    const float* w1 = (const float*)d_in[3];
    const float* b1 = (const float*)d_in[4];
    const float* w2 = (const float*)d_in[5];
    const float* b2 = (const float*)d_in[6];
    float* out = (float*)d_out;

    int N = in_sizes[0] / HF;    // 50000
    int E = in_sizes[2] / 2;     // 600000
    const int* tgt = ei + E;     // edge_index[1]

    // ws layout: counts[N] | offsets[N+1] | bsum[64] | edge_list[E] | aggb[N*HF bf16]
    size_t ints = (size_t)N + (N + 1) + 64 + E;
    size_t needed = ints * 4 + 16 + (size_t)N * HF * 2;
    if (ws_size >= needed) {
        int* counts    = (int*)d_ws;
        int* offsets   = counts + N;
        int* bsum      = offsets + N + 1;
        int* edge_list = bsum + 64;
        uintptr_t p = (uintptr_t)(edge_list + E);
        p = (p + 15) & ~(uintptr_t)15;
        unsigned short* aggb = (unsigned short*)p;

        hipMemsetAsync(counts, 0, (size_t)N * sizeof(int), stream);

        int eb = (E + 255) / 256;
        int nb = (N + 1023) / 1024;   // 49
        hist_kernel<<<eb, 256, 0, stream>>>(tgt, counts, E);
        scan1_kernel<<<nb, 1024, 0, stream>>>(counts, offsets, bsum, N);
        scan23_kernel<<<nb, 1024, 0, stream>>>(offsets, bsum, N, E, nb);
        fill_kernel<<<eb, 256, 0, stream>>>(tgt, offsets, counts, edge_list, E);

        gather_kernel<<<(N + 3) / 4, 256, 0, stream>>>(e, edge_list, offsets, aggb, N);

        int ngroups = (N + HF - 1) / HF;  // 391
        mlp_mfma_kernel<<<256, 512, 0, stream>>>(aggb, v, w1, b1, w2, b2, out, N, ngroups);
    } else {
        hipMemsetAsync(out, 0, (size_t)N * HF * sizeof(float), stream);
        long long total_t = (long long)E * 32;
        scatter_add_kernel<<<(int)((total_t + 255) / 256), 256, 0, stream>>>(e, tgt, out, E);
        mlp_kernel<<<512, 512, 0, stream>>>(out, v, w1, b1, w2, b2, N);
    }
}

// Round 5
// 207.454 us; speedup vs baseline: 5.5502x; 1.0136x over previous
//
#include <hip/hip_runtime.h>
#include <math.h>

#define HF 128
#define WPAD 136      // padded LDS row stride (bf16 elems): 272 B = 16B-multiple, 2-way banks only (free)

typedef short bfrag __attribute__((ext_vector_type(8)));   // 8 bf16 (4 VGPRs) - MFMA A/B frag
typedef float facc  __attribute__((ext_vector_type(4)));   // 4 f32 - MFMA C/D frag
typedef float f4v   __attribute__((ext_vector_type(4)));   // vector float4 (for nontemporal builtins)

__device__ __forceinline__ unsigned short f2bf(float x) {
    unsigned int u = __float_as_uint(x);
    unsigned int r = (u + 0x7FFFu + ((u >> 16) & 1u)) >> 16;
    return (unsigned short)r;
}

__device__ __forceinline__ float ssp(float x) {
    const float SHIFT = 0.69314718055994531f;
    return (x > 0.f) ? (x + log1pf(expf(-x)) - SHIFT)
                     : (log1pf(expf(x)) - SHIFT);
}

// ---------------------------------------------------------------------------
// CSR build
// ---------------------------------------------------------------------------
__global__ void hist_kernel(const int* __restrict__ tgt, int* __restrict__ counts, int E) {
    int eid = blockIdx.x * blockDim.x + threadIdx.x;
    if (eid < E) atomicAdd(&counts[tgt[eid]], 1);
}

// block-local exclusive scan; bsum[b] = block total
__global__ __launch_bounds__(1024) void scan1_kernel(const int* __restrict__ counts,
                                                     int* __restrict__ offsets,
                                                     int* __restrict__ bsum, int N) {
    __shared__ int ws[16];
    int t = threadIdx.x;
    int i = blockIdx.x * 1024 + t;
    int lane = t & 63, wv = t >> 6;
    int val = (i < N) ? counts[i] : 0;
    int x = val;
    #pragma unroll
    for (int d = 1; d < 64; d <<= 1) {
        int y = __shfl_up(x, d, 64);
        if (lane >= d) x += y;
    }
    if (lane == 63) ws[wv] = x;
    __syncthreads();
    if (wv == 0) {
        int s = (lane < 16) ? ws[lane] : 0;
        #pragma unroll
        for (int d = 1; d < 16; d <<= 1) {
            int y = __shfl_up(s, d, 64);
            if (lane >= d) s += y;
        }
        if (lane < 16) ws[lane] = s;
    }
    __syncthreads();
    int pre = ((wv > 0) ? ws[wv - 1] : 0) + (x - val);
    if (i < N) offsets[i] = pre;
    if (t == 0) bsum[blockIdx.x] = ws[15];
}

// fused: block b adds exclusive-prefix of bsum[0..b) (recomputed by wave 0), sets offsets[N]
__global__ __launch_bounds__(1024) void scan23_kernel(int* __restrict__ offsets,
                                                      const int* __restrict__ bsum,
                                                      int N, int E, int nb) {
    __shared__ int pre_s;
    int t = threadIdx.x;
    if (t < 64) {
        int v = (t < nb && t < (int)blockIdx.x) ? bsum[t] : 0;
        #pragma unroll
        for (int d = 32; d > 0; d >>= 1) v += __shfl_down(v, d, 64);
        if (t == 0) pre_s = v;
    }
    __syncthreads();
    int i = blockIdx.x * 1024 + t;
    if (i < N) offsets[i] += pre_s;
    if (blockIdx.x == 0 && t == 0) offsets[N] = E;
}

// counts doubles as cursor: atomicSub yields a unique slot in [0, count)
__global__ void fill_kernel(const int* __restrict__ tgt, const int* __restrict__ offsets,
                            int* __restrict__ counts, int* __restrict__ edge_list, int E) {
    int eid = blockIdx.x * blockDim.x + threadIdx.x;
    if (eid >= E) return;
    int t = tgt[eid];
    int pos = atomicSub(&counts[t], 1) - 1;
    edge_list[offsets[t] + pos] = eid;
}

// ---------------------------------------------------------------------------
// Gather-sum into bf16 agg: one wave per node. Main loop: 8 edges per iter,
// 4 per lane-half, 4 independent row loads in flight per lane (4 KB/wave).
// Then a 4-edge step and a 2-edge tail. Nontemporal row loads (read-once).
// ---------------------------------------------------------------------------
__global__ __launch_bounds__(256) void gather_kernel(const float* __restrict__ e,
                                                     const int* __restrict__ edge_list,
                                                     const int* __restrict__ offsets,
                                                     unsigned short* __restrict__ aggb, int N) {
    int wid = (blockIdx.x * blockDim.x + threadIdx.x) >> 6;
    if (wid >= N) return;
    int lane  = threadIdx.x & 63;
    int half  = lane >> 5;     // lane-half
    int chunk = lane & 31;     // float4 chunk within the 128-wide row
    int beg = offsets[wid], end = offsets[wid + 1];
    f4v acc0 = {0.f, 0.f, 0.f, 0.f};
    f4v acc1 = {0.f, 0.f, 0.f, 0.f};
    f4v acc2 = {0.f, 0.f, 0.f, 0.f};
    f4v acc3 = {0.f, 0.f, 0.f, 0.f};
    int j = beg;
    // main: 8 edges per iteration (4 per half), ids then rows issued back-to-back
    for (; j + 8 <= end; j += 8) {
        int ib = j + half * 4;
        int ea = edge_list[ib + 0];
        int eb = edge_list[ib + 1];
        int ec = edge_list[ib + 2];
        int ed = edge_list[ib + 3];
        f4v ra = __builtin_nontemporal_load((const f4v*)(e + (size_t)ea * HF) + chunk);
        f4v rb = __builtin_nontemporal_load((const f4v*)(e + (size_t)eb * HF) + chunk);
        f4v rc = __builtin_nontemporal_load((const f4v*)(e + (size_t)ec * HF) + chunk);
        f4v rd = __builtin_nontemporal_load((const f4v*)(e + (size_t)ed * HF) + chunk);
        acc0 += ra; acc1 += rb; acc2 += rc; acc3 += rd;
    }
    // 4-edge step (2 per half)
    if (j + 4 <= end) {
        int ib = j + half * 2;
        int ea = edge_list[ib + 0];
        int eb = edge_list[ib + 1];
        f4v ra = __builtin_nontemporal_load((const f4v*)(e + (size_t)ea * HF) + chunk);
        f4v rb = __builtin_nontemporal_load((const f4v*)(e + (size_t)eb * HF) + chunk);
        acc0 += ra; acc1 += rb;
        j += 4;
    }
    // tail: 0..3 edges (2 per iter, 1 per half)
    for (; j < end; j += 2) {
        int jj = j + half;
        if (jj < end) {
            int ec2 = edge_list[jj];
            acc2 += __builtin_nontemporal_load((const f4v*)(e + (size_t)ec2 * HF) + chunk);
        }
    }
    acc0 += acc1; acc2 += acc3; acc0 += acc2;
    acc0.x += __shfl_down(acc0.x, 32, 64);
    acc0.y += __shfl_down(acc0.y, 32, 64);
    acc0.z += __shfl_down(acc0.z, 32, 64);
    acc0.w += __shfl_down(acc0.w, 32, 64);
    if (lane < 32) {
        ushort4 o;
        o.x = f2bf(acc0.x); o.y = f2bf(acc0.y); o.z = f2bf(acc0.z); o.w = f2bf(acc0.w);
        ((ushort4*)(aggb + (size_t)wid * HF))[chunk] = o;
    }
}

// ---------------------------------------------------------------------------
// MFMA MLP: out = v + ( ssp(agg @ w1 + b1) @ w2 + b2 )
// 512 thr (8 waves), 128-node tiles. wave w: rows (w&3)*32, cols (w>>2)*64.
// 16x16x32 bf16 MFMA; C/D: col=lane&15, row=4*(lane>>4)+i  [guide m89].
// ---------------------------------------------------------------------------
__global__ __launch_bounds__(512) void mlp_mfma_kernel(
        const unsigned short* __restrict__ aggb,
        const float* __restrict__ v,
        const float* __restrict__ w1, const float* __restrict__ b1,
        const float* __restrict__ w2, const float* __restrict__ b2,
        float* __restrict__ out, int N, int ngroups) {
    __shared__ unsigned short wt1[HF * WPAD];    // w1 transposed: wt1[n][k], 34 KB
    __shared__ unsigned short wt2[HF * WPAD];    // 34 KB
    __shared__ unsigned short atile[HF * WPAD];  // agg tile, reused for h tile (34 KB)

    int tid = threadIdx.x;
    for (int idx = tid; idx < HF * HF; idx += 512) {
        int k = idx >> 7, n = idx & 127;
        wt1[n * WPAD + k] = f2bf(w1[idx]);
        wt2[n * WPAD + k] = f2bf(w2[idx]);
    }

    int w = tid >> 6, lane = tid & 63;
    int wr = (w & 3) * 32;       // row block base
    int wchalf = (w >> 2) * 64;  // col half base
    int lr = lane & 15;
    int kg = lane >> 4;          // k-group 0..3
    float bias1[4], bias2[4];
    #pragma unroll
    for (int nt = 0; nt < 4; ++nt) {
        int col = wchalf + nt * 16 + lr;
        bias1[nt] = b1[col];
        bias2[nt] = b2[col];
    }

    for (int g = blockIdx.x; g < ngroups; g += gridDim.x) {
        int base = g * HF;
        __syncthreads();   // previous iteration's tile reads done (covers weight staging, 1st iter)

        for (int idx = tid; idx < HF * 16; idx += 512) {
            int r = idx >> 4, c = idx & 15;
            int row = base + r;
            bfrag val = {0,0,0,0,0,0,0,0};
            if (row < N) val = *(const bfrag*)(aggb + (size_t)row * HF + c * 8);
            *(bfrag*)(atile + r * WPAD + c * 8) = val;
        }
        __syncthreads();

        // pass A: h = ssp(agg @ w1 + b1)
        facc acc[2][4];
        #pragma unroll
        for (int m = 0; m < 2; ++m)
            #pragma unroll
            for (int nt = 0; nt < 4; ++nt)
                acc[m][nt] = (facc){0.f, 0.f, 0.f, 0.f};
        #pragma unroll
        for (int ks = 0; ks < 4; ++ks) {
            int k0 = ks * 32 + kg * 8;
            bfrag a0 = *(const bfrag*)(atile + (wr + lr) * WPAD + k0);
            bfrag a1 = *(const bfrag*)(atile + (wr + 16 + lr) * WPAD + k0);
            #pragma unroll
            for (int nt = 0; nt < 4; ++nt) {
                bfrag b = *(const bfrag*)(wt1 + (wchalf + nt * 16 + lr) * WPAD + k0);
                acc[0][nt] = __builtin_amdgcn_mfma_f32_16x16x32_bf16(a0, b, acc[0][nt], 0, 0, 0);
                acc[1][nt] = __builtin_amdgcn_mfma_f32_16x16x32_bf16(a1, b, acc[1][nt], 0, 0, 0);
            }
        }
        __syncthreads();   // atile reads done, safe to overwrite with h

        #pragma unroll
        for (int m = 0; m < 2; ++m) {
            int rbase = wr + m * 16 + kg * 4;
            #pragma unroll
            for (int nt = 0; nt < 4; ++nt) {
                int col = wchalf + nt * 16 + lr;
                #pragma unroll
                for (int i = 0; i < 4; ++i) {
                    float h = ssp(acc[m][nt][i] + bias1[nt]);
                    atile[(rbase + i) * WPAD + col] = f2bf(h);
                }
            }
        }
        __syncthreads();

        // pass B: out = v + h @ w2 + b2
        facc acc2[2][4];
        #pragma unroll
        for (int m = 0; m < 2; ++m)
            #pragma unroll
            for (int nt = 0; nt < 4; ++nt)
                acc2[m][nt] = (facc){0.f, 0.f, 0.f, 0.f};
        #pragma unroll
        for (int ks = 0; ks < 4; ++ks) {
            int k0 = ks * 32 + kg * 8;
            bfrag a0 = *(const bfrag*)(atile + (wr + lr) * WPAD + k0);
            bfrag a1 = *(const bfrag*)(atile + (wr + 16 + lr) * WPAD + k0);
            #pragma unroll
            for (int nt = 0; nt < 4; ++nt) {
                bfrag b = *(const bfrag*)(wt2 + (wchalf + nt * 16 + lr) * WPAD + k0);
                acc2[0][nt] = __builtin_amdgcn_mfma_f32_16x16x32_bf16(a0, b, acc2[0][nt], 0, 0, 0);
                acc2[1][nt] = __builtin_amdgcn_mfma_f32_16x16x32_bf16(a1, b, acc2[1][nt], 0, 0, 0);
            }
        }

        #pragma unroll
        for (int m = 0; m < 2; ++m) {
            #pragma unroll
            for (int i = 0; i < 4; ++i) {
                int row = base + wr + m * 16 + kg * 4 + i;
                if (row < N) {
                    #pragma unroll
                    for (int nt = 0; nt < 4; ++nt) {
                        int col = wchalf + nt * 16 + lr;
                        out[(size_t)row * HF + col] = acc2[m][nt][i] + bias2[nt] + v[(size_t)row * HF + col];
                    }
                }
            }
        }
    }
}

// ---------------------------------------------------------------------------
// Fallback path (ws too small): atomic scatter + f32 vector MLP
// ---------------------------------------------------------------------------
__global__ void scatter_add_kernel(const float* __restrict__ e,
                                   const int* __restrict__ tgt,
                                   float* __restrict__ agg, int E) {
    int t = blockIdx.x * blockDim.x + threadIdx.x;
    int eid = t >> 5;
    if (eid >= E) return;
    int c = t & 31;
    int dst = tgt[eid];
    float4 val = *reinterpret_cast<const float4*>(e + (size_t)eid * HF + c * 4);
    float* p = agg + (size_t)dst * HF + c * 4;
    unsafeAtomicAdd(p + 0, val.x);
    unsafeAtomicAdd(p + 1, val.y);
    unsafeAtomicAdd(p + 2, val.z);
    unsafeAtomicAdd(p + 3, val.w);
}

__device__ __forceinline__ void fma4(float4& acc, float a, const float4& w) {
    acc.x = fmaf(a, w.x, acc.x);
    acc.y = fmaf(a, w.y, acc.y);
    acc.z = fmaf(a, w.z, acc.z);
    acc.w = fmaf(a, w.w, acc.w);
}

__global__ __launch_bounds__(512) void mlp_kernel(
        float* __restrict__ data, const float* __restrict__ v,
        const float* __restrict__ w1, const float* __restrict__ b1,
        const float* __restrict__ w2, const float* __restrict__ b2, int N) {
    __shared__ float w1s[HF * HF];
    __shared__ float w2s[HF * HF];
    __shared__ float tile[32][HF];
    int tid = threadIdx.x;
    float4* w1sv = (float4*)w1s; float4* w2sv = (float4*)w2s;
    for (int i = tid; i < HF * HF / 4; i += 512) {
        w1sv[i] = ((const float4*)w1)[i];
        w2sv[i] = ((const float4*)w2)[i];
    }
    int nl = tid >> 5, fblk = tid & 31;
    float4 bb1 = ((const float4*)b1)[fblk];
    float4 bb2 = ((const float4*)b2)[fblk];
    float4* tilev = (float4*)tile;
    int ngroups = (N + 31) / 32;
    for (int g = blockIdx.x; g < ngroups; g += gridDim.x) {
        int base = g * 32;
        __syncthreads();
        for (int i = tid; i < 32 * (HF / 4); i += 512) {
            int node = base + (i >> 5);
            float4 val = make_float4(0.f, 0.f, 0.f, 0.f);
            if (node < N) val = ((const float4*)data)[(size_t)node * (HF / 4) + (i & 31)];
            tilev[i] = val;
        }
        __syncthreads();
        float4 a0 = bb1, a1 = bb1;
        #pragma unroll 8
        for (int k = 0; k < HF; ++k) {
            float x0 = tile[nl][k], x1 = tile[nl + 16][k];
            float4 w = w1sv[k * 32 + fblk];
            fma4(a0, x0, w); fma4(a1, x1, w);
        }
        a0.x = ssp(a0.x); a0.y = ssp(a0.y); a0.z = ssp(a0.z); a0.w = ssp(a0.w);
        a1.x = ssp(a1.x); a1.y = ssp(a1.y); a1.z = ssp(a1.z); a1.w = ssp(a1.w);
        __syncthreads();
        tilev[nl * 32 + fblk] = a0;
        tilev[(nl + 16) * 32 + fblk] = a1;
        __syncthreads();
        float4 c0 = bb2, c1 = bb2;
        #pragma unroll 8
        for (int k = 0; k < HF; ++k) {
            float x0 = tile[nl][k], x1 = tile[nl + 16][k];
            float4 w = w2sv[k * 32 + fblk];
            fma4(c0, x0, w); fma4(c1, x1, w);
        }
        int n0 = base + nl, n1 = base + nl + 16;
        if (n0 < N) {
            float4 vv = ((const float4*)v)[(size_t)n0 * 32 + fblk];
            c0.x += vv.x; c0.y += vv.y; c0.z += vv.z; c0.w += vv.w;
            ((float4*)data)[(size_t)n0 * 32 + fblk] = c0;
        }
        if (n1 < N) {
            float4 vv = ((const float4*)v)[(size_t)n1 * 32 + fblk];
            c1.x += vv.x; c1.y += vv.y; c1.z += vv.z; c1.w += vv.w;
            ((float4*)data)[(size_t)n1 * 32 + fblk] = c1;
        }
    }
}

extern "C" void kernel_launch(void* const* d_in, const int* in_sizes, int n_in,
                              void* d_out, int out_size, void* d_ws, size_t ws_size,
                              hipStream_t stream) {
    const float* v  = (const float*)d_in[0];
    const float* e  = (const float*)d_in[1];
    const int*   ei = (const int*)d_in[2];
    const float* w1 = (const float*)d_in[3];
    const float* b1 = (const float*)d_in[4];
    const float* w2 = (const float*)d_in[5];
    const float* b2 = (const float*)d_in[6];
    float* out = (float*)d_out;

    int N = in_sizes[0] / HF;    // 50000
    int E = in_sizes[2] / 2;     // 600000
    const int* tgt = ei + E;     // edge_index[1]

    // ws layout: counts[N] | offsets[N+1] | bsum[64] | edge_list[E] | aggb[N*HF bf16]
    size_t ints = (size_t)N + (N + 1) + 64 + E;
    size_t needed = ints * 4 + 16 + (size_t)N * HF * 2;
    if (ws_size >= needed) {
        int* counts    = (int*)d_ws;
        int* offsets   = counts + N;
        int* bsum      = offsets + N + 1;
        int* edge_list = bsum + 64;
        uintptr_t p = (uintptr_t)(edge_list + E);
        p = (p + 15) & ~(uintptr_t)15;
        unsigned short* aggb = (unsigned short*)p;

        hipMemsetAsync(counts, 0, (size_t)N * sizeof(int), stream);

        int eb = (E + 255) / 256;
        int nb = (N + 1023) / 1024;   // 49
        hist_kernel<<<eb, 256, 0, stream>>>(tgt, counts, E);
        scan1_kernel<<<nb, 1024, 0, stream>>>(counts, offsets, bsum, N);
        scan23_kernel<<<nb, 1024, 0, stream>>>(offsets, bsum, N, E, nb);
        fill_kernel<<<eb, 256, 0, stream>>>(tgt, offsets, counts, edge_list, E);

        gather_kernel<<<(N + 3) / 4, 256, 0, stream>>>(e, edge_list, offsets, aggb, N);

        int ngroups = (N + HF - 1) / HF;  // 391
        mlp_mfma_kernel<<<256, 512, 0, stream>>>(aggb, v, w1, b1, w2, b2, out, N, ngroups);
    } else {
        hipMemsetAsync(out, 0, (size_t)N * HF * sizeof(float), stream);
        long long total_t = (long long)E * 32;
        scatter_add_kernel<<<(int)((total_t + 255) / 256), 256, 0, stream>>>(e, tgt, out, E);
        mlp_kernel<<<512, 512, 0, stream>>>(out, v, w1, b1, w2, b2, N);
    }
}